// Round 1
// baseline (14755.811 us; speedup 1.0000x reference)
//
#include <hip/hip_runtime.h>
#include <hip/hip_bf16.h>
#include <math.h>

#define B_ 4
#define L_ 60
#define H_ 768
#define I_ 1536
#define N_ 16
#define R_ 48
#define LYR_ 32

static __device__ __forceinline__ float sigmoidf_(float x) {
    return 1.f / (1.f + __expf(-x));
}

// ---------------------------------------------------------------------------
// Generic tiled fp32 GEMM: C[M,N] = act(A[M,K](lda) @ W[K,N](ldw) + bias) + res
// ACT: 0=none, 1=relu, 2=softplus, 3=tanh
// ---------------------------------------------------------------------------
#define BM 32
#define BN 32
#define BK 32

template <int ACT>
__global__ void gemm_k(const float* __restrict__ A, int lda,
                       const float* __restrict__ W, int ldw,
                       const float* __restrict__ bias,
                       const float* __restrict__ res,
                       float* __restrict__ C, int ldc,
                       int M, int N, int K) {
    __shared__ float As[BK][BM + 1];
    __shared__ float Bs[BK][BN + 1];
    int tid = threadIdx.x;
    int tx = tid & 15;        // col group
    int ty = tid >> 4;        // row group
    int block_row = blockIdx.y * BM;
    int block_col = blockIdx.x * BN;
    float acc00 = 0.f, acc01 = 0.f, acc10 = 0.f, acc11 = 0.f;

    for (int k0 = 0; k0 < K; k0 += BK) {
#pragma unroll
        for (int i = 0; i < 4; i++) {
            int idx = tid + i * 256;
            int m = idx >> 5, kk = idx & 31;
            int gm = block_row + m, gk = k0 + kk;
            As[kk][m] = (gm < M && gk < K) ? A[(size_t)gm * lda + gk] : 0.f;
        }
#pragma unroll
        for (int i = 0; i < 4; i++) {
            int idx = tid + i * 256;
            int kk = idx >> 5, n = idx & 31;
            int gk = k0 + kk, gn = block_col + n;
            Bs[kk][n] = (gk < K && gn < N) ? W[(size_t)gk * ldw + gn] : 0.f;
        }
        __syncthreads();
#pragma unroll
        for (int kk = 0; kk < BK; kk++) {
            float a0 = As[kk][ty * 2], a1 = As[kk][ty * 2 + 1];
            float b0 = Bs[kk][tx * 2], b1 = Bs[kk][tx * 2 + 1];
            acc00 += a0 * b0; acc01 += a0 * b1;
            acc10 += a1 * b0; acc11 += a1 * b1;
        }
        __syncthreads();
    }

    float accs[2][2] = {{acc00, acc01}, {acc10, acc11}};
#pragma unroll
    for (int im = 0; im < 2; im++) {
#pragma unroll
        for (int in2 = 0; in2 < 2; in2++) {
            int gm = block_row + ty * 2 + im;
            int gn = block_col + tx * 2 + in2;
            if (gm < M && gn < N) {
                float v = accs[im][in2];
                if (bias) v += bias[gn];
                if (res) v += res[(size_t)gm * ldc + gn];
                if (ACT == 1) v = fmaxf(v, 0.f);
                else if (ACT == 2) v = (v > 20.f) ? v : log1pf(__expf(v));
                else if (ACT == 3) v = tanhf(v);
                C[(size_t)gm * ldc + gn] = v;
            }
        }
    }
}

// ---------------------------------------------------------------------------
// RMSNorm over rows of 768: out = x * rsqrt(mean(x^2)+eps) * w
// grid = nrows, block = 256
// ---------------------------------------------------------------------------
__global__ void rmsnorm_kernel(const float* __restrict__ x,
                               const float* __restrict__ w,
                               float* __restrict__ out) {
    int row = blockIdx.x;
    const float* xr = x + (size_t)row * H_;
    int t = threadIdx.x;
    float v0 = xr[t], v1 = xr[t + 256], v2 = xr[t + 512];
    float s = v0 * v0 + v1 * v1 + v2 * v2;
#pragma unroll
    for (int o = 32; o > 0; o >>= 1) s += __shfl_xor(s, o);
    __shared__ float red[4];
    if ((t & 63) == 0) red[t >> 6] = s;
    __syncthreads();
    float tot = red[0] + red[1] + red[2] + red[3];
    float scale = rsqrtf(tot * (1.f / (float)H_) + 1e-5f);
    float* orow = out + (size_t)row * H_;
    orow[t]       = v0 * scale * w[t];
    orow[t + 256] = v1 * scale * w[t + 256];
    orow[t + 512] = v2 * scale * w[t + 512];
}

// ---------------------------------------------------------------------------
// Causal depthwise conv (K=4) + SiLU.  hs = proj[:, 0:I_] (ld 3072)
// out[b,t,i] = silu(conv_b[i] + sum_k hs[b,t+k-3,i]*conv_w[i,k])
// grid = B*L*I/256
// ---------------------------------------------------------------------------
__global__ void conv_silu_kernel(const float* __restrict__ proj,
                                 const float* __restrict__ conv_w,
                                 const float* __restrict__ conv_b,
                                 float* __restrict__ out) {
    int idx = blockIdx.x * 256 + threadIdx.x;   // exact: B*L*I = 1440*256
    int i = idx % I_;
    int row = idx / I_;     // b*L + t
    int t = row % L_;
    float4 w4 = ((const float4*)conv_w)[i];
    float acc = conv_b[i];
    const float* base = proj + (size_t)(row - t) * (2 * I_) + i;
    if (t >= 3) acc += base[(size_t)(t - 3) * (2 * I_)] * w4.x;
    if (t >= 2) acc += base[(size_t)(t - 2) * (2 * I_)] * w4.y;
    if (t >= 1) acc += base[(size_t)(t - 1) * (2 * I_)] * w4.z;
    acc += base[(size_t)t * (2 * I_)] * w4.w;
    out[idx] = acc * sigmoidf_(acc);
}

// ---------------------------------------------------------------------------
// Selective scan. 16 lanes per (b,i), one state element n per lane.
// y[b,t,i] = (sum_n state*C + hs*Dp) * silu(gate)
// grid = B*I*16/256 = 384, block = 256
// ---------------------------------------------------------------------------
__global__ void scan_kernel(const float* __restrict__ dt,    // [B*L, I]
                            const float* __restrict__ hs,    // [B*L, I]
                            const float* __restrict__ sp,    // [B*L, 80]
                            const float* __restrict__ proj,  // [B*L, 3072]
                            const float* __restrict__ A_log, // [I, 16]
                            const float* __restrict__ Dp,    // [I]
                            float* __restrict__ y) {         // [B*L, I]
    int tid = blockIdx.x * 256 + threadIdx.x;
    int g = tid >> 4;       // b*I + i
    int n = tid & 15;
    int b = g / I_;
    int i = g - b * I_;
    float Av = -__expf(A_log[i * N_ + n]);
    float Dv = Dp[i];
    float state = 0.f;
    for (int t = 0; t < L_; t++) {
        int row = b * L_ + t;
        float dtv = dt[(size_t)row * I_ + i];
        float xv  = hs[(size_t)row * I_ + i];
        float Bv  = sp[row * 80 + R_ + n];
        float Cv  = sp[row * 80 + R_ + N_ + n];
        state = __expf(dtv * Av) * state + (dtv * xv) * Bv;
        float p = state * Cv;
        p += __shfl_xor(p, 1, 16);
        p += __shfl_xor(p, 2, 16);
        p += __shfl_xor(p, 4, 16);
        p += __shfl_xor(p, 8, 16);
        if (n == 0) {
            float gate = proj[(size_t)row * (2 * I_) + I_ + i];
            y[(size_t)row * I_ + i] = (p + xv * Dv) * (gate * sigmoidf_(gate));
        }
    }
}

// ---------------------------------------------------------------------------
// Attention pooling: per (b,r) compute s2[l] = s1[b,l,:] @ ws2[:,r],
// softmax over l, write attn[b,l,r].  grid = B*RR = 16, block = 64
// ---------------------------------------------------------------------------
__global__ void pool_attn_kernel(const float* __restrict__ s1,   // [B*L,128]
                                 const float* __restrict__ ws2,  // [128,4]
                                 float* __restrict__ attn) {     // [B*L,4]
    int br = blockIdx.x;
    int b = br >> 2, r = br & 3;
    int l = threadIdx.x;
    float v = -1e30f;
    if (l < L_) {
        const float* row = s1 + (size_t)(b * L_ + l) * 128;
        float acc = 0.f;
        for (int d = 0; d < 128; d++) acc += row[d] * ws2[d * 4 + r];
        v = acc;
    }
    float m = v;
#pragma unroll
    for (int o = 32; o > 0; o >>= 1) m = fmaxf(m, __shfl_xor(m, o));
    float e = (l < L_) ? __expf(v - m) : 0.f;
    float ssum = e;
#pragma unroll
    for (int o = 32; o > 0; o >>= 1) ssum += __shfl_xor(ssum, o);
    if (l < L_) attn[(size_t)(b * L_ + l) * 4 + r] = e / ssum;
}

// ---------------------------------------------------------------------------
// m[b,r,h] = sum_l attn[b,l,r] * hf[b,l,h]; write flat[b, r*H + h]
// grid = 16, block = 768
// ---------------------------------------------------------------------------
__global__ void pool_m_kernel(const float* __restrict__ attn,
                              const float* __restrict__ hf,
                              float* __restrict__ flat) {
    int br = blockIdx.x;
    int b = br >> 2, r = br & 3;
    int hh = threadIdx.x;
    __shared__ float a[L_];
    if (threadIdx.x < L_) a[threadIdx.x] = attn[(size_t)(b * L_ + threadIdx.x) * 4 + r];
    __syncthreads();
    float acc = 0.f;
    for (int l = 0; l < L_; l++) acc += a[l] * hf[(size_t)(b * L_ + l) * H_ + hh];
    flat[(size_t)b * (4 * H_) + r * H_ + hh] = acc;
}

// ---------------------------------------------------------------------------

static inline int cdiv(int a, int b) { return (a + b - 1) / b; }

extern "C" void kernel_launch(void* const* d_in, const int* in_sizes, int n_in,
                              void* d_out, int out_size, void* d_ws, size_t ws_size,
                              hipStream_t stream) {
    const float* x      = (const float*)d_in[0];
    const float* iw1    = (const float*)d_in[1];
    const float* ib1    = (const float*)d_in[2];
    const float* iw2    = (const float*)d_in[3];
    const float* ib2    = (const float*)d_in[4];
    const float* iw3    = (const float*)d_in[5];
    const float* ib3    = (const float*)d_in[6];
    const float* norm_w = (const float*)d_in[7];
    const float* in_w   = (const float*)d_in[8];
    const float* conv_w = (const float*)d_in[9];
    const float* conv_b = (const float*)d_in[10];
    const float* xp_w   = (const float*)d_in[11];
    const float* dt_w   = (const float*)d_in[12];
    const float* dt_b   = (const float*)d_in[13];
    const float* A_log  = (const float*)d_in[14];
    const float* Dp     = (const float*)d_in[15];
    const float* out_w  = (const float*)d_in[16];
    const float* fnorm_w= (const float*)d_in[17];
    const float* ws1    = (const float*)d_in[18];
    const float* ws2    = (const float*)d_in[19];
    const float* ow1    = (const float*)d_in[20];
    const float* ob1    = (const float*)d_in[21];
    const float* ow2    = (const float*)d_in[22];
    const float* ob2    = (const float*)d_in[23];
    const float* ow3    = (const float*)d_in[24];
    const float* ob3    = (const float*)d_in[25];

    float* out = (float*)d_out;

    const int BL = B_ * L_;   // 240

    // workspace carve-up (floats)
    float* ws   = (float*)d_ws;
    float* h    = ws;                  // BL*H    = 184320
    float* hn   = h    + BL * H_;      // 184320
    float* proj = hn   + BL * H_;      // BL*3072 = 737280
    float* hsb  = proj + BL * 2 * I_;  // BL*I    = 368640
    float* spb  = hsb  + BL * I_;      // BL*80   = 19200
    float* dtb  = spb  + BL * 80;      // 368640
    float* yb   = dtb  + BL * I_;      // 368640
    float* hf   = yb   + BL * I_;      // 184320
    float* s1b  = hf   + BL * H_;      // BL*128  = 30720
    float* attn = s1b  + BL * 128;     // 960
    float* flat = attn + BL * 4;       // 12288
    float* o1   = flat + B_ * 4 * H_;  // 1024
    float* o2   = o1   + B_ * 256;     // 1024
    float* h1   = o2   + B_ * 256;     // 61440
    float* h2   = h1   + BL * 256;     // 61440

    // ---- input MLP: x(240,13) -> 256 -> 256 -> 768
    {
        dim3 g1(cdiv(256, BN), cdiv(BL, BM));
        gemm_k<1><<<g1, 256, 0, stream>>>(x, 13, iw1, 256, ib1, nullptr, h1, 256, BL, 256, 13);
        gemm_k<1><<<g1, 256, 0, stream>>>(h1, 256, iw2, 256, ib2, nullptr, h2, 256, BL, 256, 256);
        dim3 g3(cdiv(H_, BN), cdiv(BL, BM));
        gemm_k<0><<<g3, 256, 0, stream>>>(h2, 256, iw3, H_, ib3, nullptr, h, H_, BL, H_, 256);
    }

    // ---- 32 mamba layers
    for (int l = 0; l < LYR_; l++) {
        const float* nw  = norm_w + (size_t)l * H_;
        const float* iwp = in_w   + (size_t)l * H_ * 2 * I_;
        const float* cw  = conv_w + (size_t)l * I_ * 4;
        const float* cb  = conv_b + (size_t)l * I_;
        const float* xw  = xp_w   + (size_t)l * I_ * 80;
        const float* dw  = dt_w   + (size_t)l * R_ * I_;
        const float* db  = dt_b   + (size_t)l * I_;
        const float* al  = A_log  + (size_t)l * I_ * N_;
        const float* dp  = Dp     + (size_t)l * I_;
        const float* ow  = out_w  + (size_t)l * I_ * H_;

        rmsnorm_kernel<<<BL, 256, 0, stream>>>(h, nw, hn);

        dim3 gin(cdiv(2 * I_, BN), cdiv(BL, BM));   // (96, 8)
        gemm_k<0><<<gin, 256, 0, stream>>>(hn, H_, iwp, 2 * I_, nullptr, nullptr,
                                           proj, 2 * I_, BL, 2 * I_, H_);

        conv_silu_kernel<<<BL * I_ / 256, 256, 0, stream>>>(proj, cw, cb, hsb);

        dim3 gxp(cdiv(80, BN), cdiv(BL, BM));       // (3, 8)
        gemm_k<0><<<gxp, 256, 0, stream>>>(hsb, I_, xw, 80, nullptr, nullptr,
                                           spb, 80, BL, 80, I_);

        dim3 gdt(cdiv(I_, BN), cdiv(BL, BM));       // (48, 8)
        gemm_k<2><<<gdt, 256, 0, stream>>>(spb, 80, dw, I_, db, nullptr,
                                           dtb, I_, BL, I_, R_);

        scan_kernel<<<B_ * I_ * 16 / 256, 256, 0, stream>>>(dtb, hsb, spb, proj, al, dp, yb);

        dim3 gout(cdiv(H_, BN), cdiv(BL, BM));      // (24, 8)
        gemm_k<0><<<gout, 256, 0, stream>>>(yb, I_, ow, H_, nullptr, h,
                                            h, H_, BL, H_, I_);
    }

    // ---- final norm + attention pooling
    rmsnorm_kernel<<<BL, 256, 0, stream>>>(h, fnorm_w, hf);

    dim3 gs1(cdiv(128, BN), cdiv(BL, BM));
    gemm_k<3><<<gs1, 256, 0, stream>>>(hf, H_, ws1, 128, nullptr, nullptr,
                                       s1b, 128, BL, 128, H_);

    pool_attn_kernel<<<16, 64, 0, stream>>>(s1b, ws2, attn);
    pool_m_kernel<<<16, H_, 0, stream>>>(attn, hf, flat);

    // ---- output MLP: flat(4,3072) -> 256 -> 256 -> 1
    dim3 go1(cdiv(256, BN), cdiv(B_, BM));
    gemm_k<1><<<go1, 256, 0, stream>>>(flat, 4 * H_, ow1, 256, ob1, nullptr, o1, 256, B_, 256, 4 * H_);
    gemm_k<1><<<go1, 256, 0, stream>>>(o1, 256, ow2, 256, ob2, nullptr, o2, 256, B_, 256, 256);
    dim3 go3(1, 1);
    gemm_k<0><<<go3, 256, 0, stream>>>(o2, 256, ow3, 1, ob3, nullptr, out, 1, B_, 1, 256);
}

// Round 2
// 5796.771 us; speedup vs baseline: 2.5455x; 2.5455x over previous
//
#include <hip/hip_runtime.h>
#include <hip/hip_bf16.h>
#include <math.h>

#define B_ 4
#define L_ 60
#define H_ 768
#define I_ 1536
#define N_ 16
#define R_ 48
#define LYR_ 32

static __device__ __forceinline__ float sigmoidf_(float x) {
    return 1.f / (1.f + __expf(-x));
}

// ---------------------------------------------------------------------------
// Fast fp32 GEMM: 64x64 tile, BK=16, 4x4 per thread, register-prefetch.
// C[M,N] = act(A@W + bias) + res   (or atomicAdd partial if ATOMIC)
// Requires: lda%4==0, ldw%4==0, N%64==0, (kend-kstart)%16==0, kchunk%16==0.
// NORM: A element (gm,gk) is multiplied by rowscale[gm]*nw[gk] on load
//       (fuses RMSNorm into the GEMM).
// ---------------------------------------------------------------------------
template <int ACT, bool ATOMIC, bool NORM>
__global__ __launch_bounds__(256)
void gemm64_k(const float* __restrict__ A, int lda,
              const float* __restrict__ W, int ldw,
              const float* __restrict__ bias,
              const float* __restrict__ res,
              float* __restrict__ C, int ldc,
              int M, int kstart_full, int kend_full,
              const float* __restrict__ rowscale,
              const float* __restrict__ nw) {
    __shared__ float As[16][68];
    __shared__ float Bs[16][68];
    const int tid = threadIdx.x;
    const int tx = tid & 15, ty = tid >> 4;
    const int brow = blockIdx.y * 64, bcol = blockIdx.x * 64;
    int kstart = kstart_full, kend = kend_full;
    if (gridDim.z > 1) {
        int chunk = (kend_full - kstart_full) / (int)gridDim.z;
        kstart = kstart_full + blockIdx.z * chunk;
        kend = kstart + chunk;
    }
    const int a_row = tid >> 2;        // 0..63
    const int a_kc  = (tid & 3) * 4;   // 0,4,8,12
    const int w_k   = tid >> 4;        // 0..15
    const int w_c   = (tid & 15) * 4;  // 0..60
    const int gmA = brow + a_row;

    float4 ra, rb;
    float acc[4][4] = {};

    // first stage load
    {
        if (gmA < M) {
            ra = *(const float4*)&A[(size_t)gmA * lda + kstart + a_kc];
            if (NORM) {
                float s = rowscale[gmA];
                float4 n4 = *(const float4*)&nw[kstart + a_kc];
                ra.x *= s * n4.x; ra.y *= s * n4.y; ra.z *= s * n4.z; ra.w *= s * n4.w;
            }
        } else ra = make_float4(0.f, 0.f, 0.f, 0.f);
        rb = *(const float4*)&W[(size_t)(kstart + w_k) * ldw + bcol + w_c];
    }

    for (int k0 = kstart; k0 < kend; k0 += 16) {
        As[a_kc + 0][a_row] = ra.x;
        As[a_kc + 1][a_row] = ra.y;
        As[a_kc + 2][a_row] = ra.z;
        As[a_kc + 3][a_row] = ra.w;
        *(float4*)&Bs[w_k][w_c] = rb;
        __syncthreads();
        int kn = k0 + 16;
        if (kn < kend) {   // prefetch next tile while computing
            if (gmA < M) {
                ra = *(const float4*)&A[(size_t)gmA * lda + kn + a_kc];
                if (NORM) {
                    float s = rowscale[gmA];
                    float4 n4 = *(const float4*)&nw[kn + a_kc];
                    ra.x *= s * n4.x; ra.y *= s * n4.y; ra.z *= s * n4.z; ra.w *= s * n4.w;
                }
            } else ra = make_float4(0.f, 0.f, 0.f, 0.f);
            rb = *(const float4*)&W[(size_t)(kn + w_k) * ldw + bcol + w_c];
        }
#pragma unroll
        for (int kk = 0; kk < 16; kk++) {
            float4 av = *(const float4*)&As[kk][ty * 4];
            float4 bv = *(const float4*)&Bs[kk][tx * 4];
            float a_[4] = {av.x, av.y, av.z, av.w};
            float b_[4] = {bv.x, bv.y, bv.z, bv.w};
#pragma unroll
            for (int im = 0; im < 4; im++)
#pragma unroll
                for (int in2 = 0; in2 < 4; in2++)
                    acc[im][in2] += a_[im] * b_[in2];
        }
        __syncthreads();
    }

#pragma unroll
    for (int im = 0; im < 4; im++) {
        int gm = brow + ty * 4 + im;
        if (gm < M) {
            if (ATOMIC) {
#pragma unroll
                for (int in2 = 0; in2 < 4; in2++)
                    atomicAdd(&C[(size_t)gm * ldc + bcol + tx * 4 + in2], acc[im][in2]);
            } else {
                float4 v;
                float* vp = &v.x;
#pragma unroll
                for (int in2 = 0; in2 < 4; in2++) {
                    int gn = bcol + tx * 4 + in2;
                    float t = acc[im][in2];
                    if (bias) t += bias[gn];
                    if (res) t += res[(size_t)gm * ldc + gn];
                    if (ACT == 1) t = fmaxf(t, 0.f);
                    else if (ACT == 2) t = (t > 20.f) ? t : log1pf(__expf(t));
                    vp[in2] = t;
                }
                *(float4*)&C[(size_t)gm * ldc + bcol + tx * 4] = v;
            }
        }
    }
}

// ---------------------------------------------------------------------------
// Generic small GEMM: 32x32 tile, 2x2/thread, bounds-safe, optional split-K.
// ACT: 0=none, 1=relu, 2=softplus
// ---------------------------------------------------------------------------
#define BM 32
#define BN 32
#define BK 32

template <int ACT, bool ATOMIC>
__global__ __launch_bounds__(256)
void gemm_k(const float* __restrict__ A, int lda,
            const float* __restrict__ W, int ldw,
            const float* __restrict__ bias,
            const float* __restrict__ res,
            float* __restrict__ C, int ldc,
            int M, int N, int K) {
    __shared__ float As[BK][BM + 1];
    __shared__ float Bs[BK][BN + 1];
    int tid = threadIdx.x;
    int tx = tid & 15;
    int ty = tid >> 4;
    int block_row = blockIdx.y * BM;
    int block_col = blockIdx.x * BN;
    int kbeg = 0, kend = K;
    if (gridDim.z > 1) {
        int chunk = K / (int)gridDim.z;
        kbeg = blockIdx.z * chunk;
        kend = kbeg + chunk;
    }
    float acc00 = 0.f, acc01 = 0.f, acc10 = 0.f, acc11 = 0.f;

    for (int k0 = kbeg; k0 < kend; k0 += BK) {
#pragma unroll
        for (int i = 0; i < 4; i++) {
            int idx = tid + i * 256;
            int m = idx >> 5, kk = idx & 31;
            int gm = block_row + m, gk = k0 + kk;
            As[kk][m] = (gm < M && gk < kend) ? A[(size_t)gm * lda + gk] : 0.f;
        }
#pragma unroll
        for (int i = 0; i < 4; i++) {
            int idx = tid + i * 256;
            int kk = idx >> 5, n = idx & 31;
            int gk = k0 + kk, gn = block_col + n;
            Bs[kk][n] = (gk < kend && gn < N) ? W[(size_t)gk * ldw + gn] : 0.f;
        }
        __syncthreads();
#pragma unroll
        for (int kk = 0; kk < BK; kk++) {
            float a0 = As[kk][ty * 2], a1 = As[kk][ty * 2 + 1];
            float b0 = Bs[kk][tx * 2], b1 = Bs[kk][tx * 2 + 1];
            acc00 += a0 * b0; acc01 += a0 * b1;
            acc10 += a1 * b0; acc11 += a1 * b1;
        }
        __syncthreads();
    }

    float accs[2][2] = {{acc00, acc01}, {acc10, acc11}};
#pragma unroll
    for (int im = 0; im < 2; im++) {
#pragma unroll
        for (int in2 = 0; in2 < 2; in2++) {
            int gm = block_row + ty * 2 + im;
            int gn = block_col + tx * 2 + in2;
            if (gm < M && gn < N) {
                float v = accs[im][in2];
                if (ATOMIC) {
                    atomicAdd(&C[(size_t)gm * ldc + gn], v);
                } else {
                    if (bias) v += bias[gn];
                    if (res) v += res[(size_t)gm * ldc + gn];
                    if (ACT == 1) v = fmaxf(v, 0.f);
                    else if (ACT == 2) v = (v > 20.f) ? v : log1pf(__expf(v));
                    C[(size_t)gm * ldc + gn] = v;
                }
            }
        }
    }
}

// ---------------------------------------------------------------------------
// Per-row RMS scale: rs[row] = rsqrt(mean(x^2)+eps).  grid=nrows, block=256
// ---------------------------------------------------------------------------
__global__ void rms_scale_kernel(const float* __restrict__ x,
                                 float* __restrict__ rs) {
    int row = blockIdx.x;
    const float* xr = x + (size_t)row * H_;
    int t = threadIdx.x;
    float v0 = xr[t], v1 = xr[t + 256], v2 = xr[t + 512];
    float s = v0 * v0 + v1 * v1 + v2 * v2;
#pragma unroll
    for (int o = 32; o > 0; o >>= 1) s += __shfl_xor(s, o);
    __shared__ float red[4];
    if ((t & 63) == 0) red[t >> 6] = s;
    __syncthreads();
    if (t == 0) {
        float tot = red[0] + red[1] + red[2] + red[3];
        rs[row] = rsqrtf(tot * (1.f / (float)H_) + 1e-5f);
    }
}

// full rmsnorm (used once for hf at the end)
__global__ void rmsnorm_kernel(const float* __restrict__ x,
                               const float* __restrict__ w,
                               float* __restrict__ out) {
    int row = blockIdx.x;
    const float* xr = x + (size_t)row * H_;
    int t = threadIdx.x;
    float v0 = xr[t], v1 = xr[t + 256], v2 = xr[t + 512];
    float s = v0 * v0 + v1 * v1 + v2 * v2;
#pragma unroll
    for (int o = 32; o > 0; o >>= 1) s += __shfl_xor(s, o);
    __shared__ float red[4];
    if ((t & 63) == 0) red[t >> 6] = s;
    __syncthreads();
    float tot = red[0] + red[1] + red[2] + red[3];
    float scale = rsqrtf(tot * (1.f / (float)H_) + 1e-5f);
    float* orow = out + (size_t)row * H_;
    orow[t]       = v0 * scale * w[t];
    orow[t + 256] = v1 * scale * w[t + 256];
    orow[t + 512] = v2 * scale * w[t + 512];
}

// ---------------------------------------------------------------------------
// Causal depthwise conv (K=4) + SiLU
// ---------------------------------------------------------------------------
__global__ void conv_silu_kernel(const float* __restrict__ proj,
                                 const float* __restrict__ conv_w,
                                 const float* __restrict__ conv_b,
                                 float* __restrict__ out) {
    int idx = blockIdx.x * 256 + threadIdx.x;   // B*L*I
    int i = idx % I_;
    int row = idx / I_;
    int t = row % L_;
    float4 w4 = ((const float4*)conv_w)[i];
    float acc = conv_b[i];
    const float* base = proj + (size_t)(row - t) * (2 * I_) + i;
    if (t >= 3) acc += base[(size_t)(t - 3) * (2 * I_)] * w4.x;
    if (t >= 2) acc += base[(size_t)(t - 2) * (2 * I_)] * w4.y;
    if (t >= 1) acc += base[(size_t)(t - 1) * (2 * I_)] * w4.z;
    acc += base[(size_t)t * (2 * I_)] * w4.w;
    out[idx] = acc * sigmoidf_(acc);
}

// ---------------------------------------------------------------------------
// Selective scan; 16 lanes per (b,i), fused gating epilogue
// ---------------------------------------------------------------------------
__global__ void scan_kernel(const float* __restrict__ dt,
                            const float* __restrict__ hs,
                            const float* __restrict__ sp,
                            const float* __restrict__ proj,
                            const float* __restrict__ A_log,
                            const float* __restrict__ Dp,
                            float* __restrict__ y) {
    int tid = blockIdx.x * 256 + threadIdx.x;
    int g = tid >> 4;
    int n = tid & 15;
    int b = g / I_;
    int i = g - b * I_;
    float Av = -__expf(A_log[i * N_ + n]);
    float Dv = Dp[i];
    float state = 0.f;
    for (int t = 0; t < L_; t++) {
        int row = b * L_ + t;
        float dtv = dt[(size_t)row * I_ + i];
        float xv  = hs[(size_t)row * I_ + i];
        float Bv  = sp[row * 80 + R_ + n];
        float Cv  = sp[row * 80 + R_ + N_ + n];
        state = __expf(dtv * Av) * state + (dtv * xv) * Bv;
        float p = state * Cv;
        p += __shfl_xor(p, 1, 16);
        p += __shfl_xor(p, 2, 16);
        p += __shfl_xor(p, 4, 16);
        p += __shfl_xor(p, 8, 16);
        if (n == 0) {
            float gate = proj[(size_t)row * (2 * I_) + I_ + i];
            y[(size_t)row * I_ + i] = (p + xv * Dv) * (gate * sigmoidf_(gate));
        }
    }
}

// ---------------------------------------------------------------------------
// Attention pooling (tanh applied on read of raw s1)
// ---------------------------------------------------------------------------
__global__ void pool_attn_kernel(const float* __restrict__ s1,
                                 const float* __restrict__ ws2,
                                 float* __restrict__ attn) {
    int br = blockIdx.x;
    int b = br >> 2, r = br & 3;
    int l = threadIdx.x;
    float v = -1e30f;
    if (l < L_) {
        const float* row = s1 + (size_t)(b * L_ + l) * 128;
        float acc = 0.f;
        for (int d = 0; d < 128; d++) acc += tanhf(row[d]) * ws2[d * 4 + r];
        v = acc;
    }
    float m = v;
#pragma unroll
    for (int o = 32; o > 0; o >>= 1) m = fmaxf(m, __shfl_xor(m, o));
    float e = (l < L_) ? __expf(v - m) : 0.f;
    float ssum = e;
#pragma unroll
    for (int o = 32; o > 0; o >>= 1) ssum += __shfl_xor(ssum, o);
    if (l < L_) attn[(size_t)(b * L_ + l) * 4 + r] = e / ssum;
}

__global__ void pool_m_kernel(const float* __restrict__ attn,
                              const float* __restrict__ hf,
                              float* __restrict__ flat) {
    int br = blockIdx.x;
    int b = br >> 2, r = br & 3;
    int hh = threadIdx.x;
    __shared__ float a[L_];
    if (threadIdx.x < L_) a[threadIdx.x] = attn[(size_t)(b * L_ + threadIdx.x) * 4 + r];
    __syncthreads();
    float acc = 0.f;
    for (int l = 0; l < L_; l++) acc += a[l] * hf[(size_t)(b * L_ + l) * H_ + hh];
    flat[(size_t)b * (4 * H_) + r * H_ + hh] = acc;
}

// ---------------------------------------------------------------------------
// Fused output MLP: flat[B,3072] -> 256 (relu) -> 256 (relu) -> 1
// grid = B, block = 256
// ---------------------------------------------------------------------------
__global__ void out_mlp_kernel(const float* __restrict__ flat,
                               const float* __restrict__ ow1, const float* __restrict__ ob1,
                               const float* __restrict__ ow2, const float* __restrict__ ob2,
                               const float* __restrict__ ow3, const float* __restrict__ ob3,
                               float* __restrict__ out) {
    int b = blockIdx.x;
    int t = threadIdx.x;
    __shared__ float xs[3072];
    __shared__ float o1s[256];
    for (int i = t; i < 3072; i += 256) xs[i] = flat[(size_t)b * 3072 + i];
    __syncthreads();
    float acc = ob1[t];
    for (int d = 0; d < 3072; d++) acc += xs[d] * ow1[(size_t)d * 256 + t];
    o1s[t] = fmaxf(acc, 0.f);
    __syncthreads();
    float acc2 = ob2[t];
    for (int d = 0; d < 256; d++) acc2 += o1s[d] * ow2[(size_t)d * 256 + t];
    float v = fmaxf(acc2, 0.f) * ow3[t];
#pragma unroll
    for (int o = 32; o > 0; o >>= 1) v += __shfl_xor(v, o);
    __shared__ float red[4];
    if ((t & 63) == 0) red[t >> 6] = v;
    __syncthreads();
    if (t == 0) out[b] = red[0] + red[1] + red[2] + red[3] + ob3[0];
}

// ---------------------------------------------------------------------------

static inline int cdiv(int a, int b) { return (a + b - 1) / b; }

extern "C" void kernel_launch(void* const* d_in, const int* in_sizes, int n_in,
                              void* d_out, int out_size, void* d_ws, size_t ws_size,
                              hipStream_t stream) {
    const float* x      = (const float*)d_in[0];
    const float* iw1    = (const float*)d_in[1];
    const float* ib1    = (const float*)d_in[2];
    const float* iw2    = (const float*)d_in[3];
    const float* ib2    = (const float*)d_in[4];
    const float* iw3    = (const float*)d_in[5];
    const float* ib3    = (const float*)d_in[6];
    const float* norm_w = (const float*)d_in[7];
    const float* in_w   = (const float*)d_in[8];
    const float* conv_w = (const float*)d_in[9];
    const float* conv_b = (const float*)d_in[10];
    const float* xp_w   = (const float*)d_in[11];
    const float* dt_w   = (const float*)d_in[12];
    const float* dt_b   = (const float*)d_in[13];
    const float* A_log  = (const float*)d_in[14];
    const float* Dp     = (const float*)d_in[15];
    const float* out_w  = (const float*)d_in[16];
    const float* fnorm_w= (const float*)d_in[17];
    const float* ws1    = (const float*)d_in[18];
    const float* ws2    = (const float*)d_in[19];
    const float* ow1    = (const float*)d_in[20];
    const float* ob1    = (const float*)d_in[21];
    const float* ow2    = (const float*)d_in[22];
    const float* ob2    = (const float*)d_in[23];
    const float* ow3    = (const float*)d_in[24];
    const float* ob3    = (const float*)d_in[25];

    float* out = (float*)d_out;
    const int BL = B_ * L_;   // 240

    float* ws   = (float*)d_ws;
    float* h    = ws;                  // BL*H
    float* proj = h    + BL * H_;      // BL*3072
    float* hsb  = proj + BL * 2 * I_;  // BL*I
    float* spb  = hsb  + BL * I_;      // BL*80
    float* dtb  = spb  + BL * 80;      // BL*I
    float* yb   = dtb  + BL * I_;      // BL*I
    float* hf   = yb   + BL * I_;      // BL*H
    float* s1b  = hf   + BL * H_;      // BL*128
    float* attn = s1b  + BL * 128;     // BL*4
    float* flat = attn + BL * 4;       // B*3072
    float* h1   = flat + B_ * 4 * H_;  // BL*256
    float* h2   = h1   + BL * 256;     // BL*256
    float* rs   = h2   + BL * 256;     // BL

    // ---- input MLP: x(240,13) -> 256 -> 256 -> 768
    {
        dim3 g1(cdiv(256, BN), cdiv(BL, BM));
        gemm_k<1, false><<<g1, 256, 0, stream>>>(x, 13, iw1, 256, ib1, nullptr, h1, 256, BL, 256, 13);
        gemm_k<1, false><<<g1, 256, 0, stream>>>(h1, 256, iw2, 256, ib2, nullptr, h2, 256, BL, 256, 256);
        dim3 g3(cdiv(H_, BN), cdiv(BL, BM));
        gemm_k<0, false><<<g3, 256, 0, stream>>>(h2, 256, iw3, H_, ib3, nullptr, h, H_, BL, H_, 256);
    }

    // ---- 32 mamba layers
    for (int l = 0; l < LYR_; l++) {
        const float* nw  = norm_w + (size_t)l * H_;
        const float* iwp = in_w   + (size_t)l * H_ * 2 * I_;
        const float* cw  = conv_w + (size_t)l * I_ * 4;
        const float* cb  = conv_b + (size_t)l * I_;
        const float* xw  = xp_w   + (size_t)l * I_ * 80;
        const float* dw  = dt_w   + (size_t)l * R_ * I_;
        const float* db  = dt_b   + (size_t)l * I_;
        const float* al  = A_log  + (size_t)l * I_ * N_;
        const float* dp  = Dp     + (size_t)l * I_;
        const float* ow  = out_w  + (size_t)l * I_ * H_;

        rms_scale_kernel<<<BL, 256, 0, stream>>>(h, rs);

        // in-proj with fused rmsnorm: proj = (h*rs*nw) @ in_w   [240,3072]
        dim3 gin(2 * I_ / 64, 4, 1);   // (48,4)
        gemm64_k<0, false, true><<<gin, 256, 0, stream>>>(
            h, H_, iwp, 2 * I_, nullptr, nullptr, proj, 2 * I_,
            BL, 0, H_, rs, nw);

        conv_silu_kernel<<<BL * I_ / 256, 256, 0, stream>>>(proj, cw, cb, hsb);

        // sp = hs @ xp_w  [240,80], split-K=8 atomic
        hipMemsetAsync(spb, 0, (size_t)BL * 80 * sizeof(float), stream);
        dim3 gxp(cdiv(80, BN), cdiv(BL, BM), 8);
        gemm_k<0, true><<<gxp, 256, 0, stream>>>(hsb, I_, xw, 80, nullptr, nullptr,
                                                 spb, 80, BL, 80, I_);

        // dt = softplus(sp[:,:48] @ dt_w + dt_b)  [240,1536]
        dim3 gdt(cdiv(I_, BN), cdiv(BL, BM), 1);
        gemm_k<2, false><<<gdt, 256, 0, stream>>>(spb, 80, dw, I_, db, nullptr,
                                                  dtb, I_, BL, I_, R_);

        scan_kernel<<<B_ * I_ * 16 / 256, 256, 0, stream>>>(dtb, hsb, spb, proj, al, dp, yb);

        // h += yb @ out_w  (split-K=8, atomic accumulate, fused residual)
        dim3 gout(H_ / 64, 4, 8);      // (12,4,8)
        gemm64_k<0, true, false><<<gout, 256, 0, stream>>>(
            yb, I_, ow, H_, nullptr, nullptr, h, H_,
            BL, 0, I_, nullptr, nullptr);
    }

    // ---- final norm + attention pooling
    rmsnorm_kernel<<<BL, 256, 0, stream>>>(h, fnorm_w, hf);

    // s1 = hf @ ws1 [240,128] split-K=4 atomic (tanh applied in pool_attn)
    hipMemsetAsync(s1b, 0, (size_t)BL * 128 * sizeof(float), stream);
    dim3 gs1(cdiv(128, BN), cdiv(BL, BM), 4);
    gemm_k<0, true><<<gs1, 256, 0, stream>>>(hf, H_, ws1, 128, nullptr, nullptr,
                                             s1b, 128, BL, 128, H_);

    pool_attn_kernel<<<16, 64, 0, stream>>>(s1b, ws2, attn);
    pool_m_kernel<<<16, H_, 0, stream>>>(attn, hf, flat);

    out_mlp_kernel<<<B_, 256, 0, stream>>>(flat, ow1, ob1, ow2, ob2, ow3, ob3, out);
}